// Round 15
// baseline (205.368 us; speedup 1.0000x reference)
//
#include <hip/hip_runtime.h>

typedef unsigned short u16;
typedef unsigned int   u32;
typedef __attribute__((ext_vector_type(4))) float f32x4;
typedef __attribute__((ext_vector_type(16))) float f32x16;
typedef __attribute__((ext_vector_type(8))) short bf16x8;
typedef __attribute__((ext_vector_type(4))) unsigned short u16x4;
typedef __attribute__((ext_vector_type(8))) unsigned short u16x8;

__device__ __forceinline__ u16 f2bf(float f) {
  union { float f; u32 u; } v; v.f = f;
  u32 r = v.u + 0x7FFFu + ((v.u >> 16) & 1u);   // round-to-nearest-even
  return (u16)(r >> 16);
}

__device__ __forceinline__ float bcast(float v, int l) {
  return __uint_as_float(__builtin_amdgcn_readlane(__float_as_uint(v), l));
}

// ---------------- Kernel 1: Cayley Q = 2*(I+S)^-1 - I, S = 0.5(R - R^T) ----
__global__ __launch_bounds__(256, 1) void cayley_kernel(
    const float* __restrict__ R, float* __restrict__ Q) {
  const int b  = blockIdx.x;
  const int t  = threadIdx.x;
  const int j  = t & 63;                // column owner (lane)
  const int iw = t >> 6;                // wave = row-block owner
  __shared__ float Rl[64][65];          // staged R (padded: transpose-read free)
  __shared__ float prow[2][2][64];      // [k parity][A|B][j]
  const float* Rb = R + (size_t)b * 4096;
  for (int idx = t; idx < 4096; idx += 256)
    Rl[idx >> 6][idx & 63] = Rb[idx];
  __syncthreads();
  float Ac[16], Bc[16];                 // A[16iw+i'][j], B[16iw+i'][j]
  #pragma unroll
  for (int i2 = 0; i2 < 16; ++i2) {
    const int i = iw*16 + i2;
    float s = 0.5f * (Rl[i][j] - Rl[j][i]);
    Ac[i2] = (i == j) ? (1.0f + s) : s;
    Bc[i2] = (i == j) ? 1.0f : 0.0f;
  }
  __syncthreads();
  #pragma unroll
  for (int kb = 0; kb < 4; ++kb) {
    #pragma unroll
    for (int kp = 0; kp < 16; ++kp) {
      const int k = kb*16 + kp;         // compile-time constant
      if (iw == kb) {                   // wave-uniform: pivot wave scales row k
        float pinv = 1.0f / bcast(Ac[kp], k);
        float ar = Ac[kp] * pinv;
        float br = Bc[kp] * pinv;
        Ac[kp] = ar; Bc[kp] = br;
        prow[k & 1][0][j] = ar;
        prow[k & 1][1][j] = br;
      }
      __syncthreads();
      const float ar = prow[k & 1][0][j];
      const float br = prow[k & 1][1][j];
      #pragma unroll
      for (int i2 = 0; i2 < 16; ++i2) { // eliminate own rows (static idx)
        float f = bcast(Ac[i2], k);     // A[16iw+i2][k], pre-update (lockstep)
        if (iw == kb && i2 == kp) f = 0.0f;   // pivot row preserved
        Ac[i2] -= f * ar;
        Bc[i2] -= f * br;
      }
    }
  }
  float* Qb = Q + (size_t)b * 4096;
  #pragma unroll
  for (int i2 = 0; i2 < 16; ++i2) {
    const int i = iw*16 + i2;
    Qb[i*64 + j] = 2.0f * Bc[i2] - ((i == j) ? 1.0f : 0.0f);
  }
}

// ---------------- Kernel 2: rot superblocks -> bf16 ------------------------
__global__ __launch_bounds__(256) void rotbuild_kernel(
    const float* __restrict__ Q, u16* __restrict__ rotb) {
  const int s = blockIdx.x;
  const int t = threadIdx.x;
  __shared__ float Q1l[2][64][65];      // padded
  __shared__ f32x4 Q0l[2][64][16];      // [dh][k][c4]
  const float* Q0g = Q + (size_t)(2*s) * 4096;        // factor 0: blocks 2s,2s+1
  const float* Q1g = Q + (size_t)(64 + 2*s) * 4096;   // factor 1 starts at block 64
  for (int i = t; i < 2*4096; i += 256) {
    int e = i >> 12, r = (i >> 6) & 63, c = i & 63;
    Q1l[e][r][c] = Q1g[i];
    ((float*)&Q0l[e][r][0])[c] = Q0g[i];
  }
  __syncthreads();
  const int a_l = t & 127;
  const int dh  = t >> 7;               // c-half this thread fills
  const int g   = a_l >> 5;             // local butterfly perm (involution)
  const int pa  = a_l + ((g == 1) ? 32 : (g == 2) ? -32 : 0);
  const int e = pa >> 6, pa64 = pa & 63;
  float q1v[32];
  #pragma unroll
  for (int jj = 0; jj < 32; ++jj) q1v[jj] = Q1l[e][pa64][dh*32 + jj];
  f32x4 acc4[16] = {};
  #pragma unroll
  for (int jj = 0; jj < 32; ++jj) {
    #pragma unroll
    for (int c4 = 0; c4 < 16; ++c4)
      acc4[c4] += q1v[jj] * Q0l[dh][e*32 + jj][c4];   // broadcast LDS read
  }
  u16* dst = rotb + (size_t)s*16384 + (size_t)a_l*128 + dh*64;
  #pragma unroll
  for (int c4 = 0; c4 < 16; ++c4) {
    u16x4 o;
    o.x = f2bf(acc4[c4].x); o.y = f2bf(acc4[c4].y);
    o.z = f2bf(acc4[c4].z); o.w = f2bf(acc4[c4].w);
    *(u16x4*)&dst[c4*4] = o;
  }
}

// ---------------- Kernel 3: SW = (W @ rot^T) * s -> bf16, MFMA -------------
__global__ __launch_bounds__(256) void wtrans_kernel(
    const float* __restrict__ W, const u16* __restrict__ rotb,
    const float* __restrict__ sscale, u16* __restrict__ SW) {
  const int rt = blockIdx.x;            // row tile 0..31
  const int s  = blockIdx.y;            // superblock 0..31
  const int t  = threadIdx.x;
  __shared__ u16 Asw[128*128];          // W tile bf16, swizzled
  __shared__ u16 Bsw[128*128];          // rot_s bf16, swizzled
  // stage A: granule g: row=g>>5, gc=g&31 (f32x4). Coalesced 16B/lane.
  #pragma unroll
  for (int p = 0; p < 16; ++p) {
    const int g = p*256 + t;
    const int row = g >> 5, gc = g & 31;
    float4 v = *(const float4*)(W + (size_t)(rt*128 + row)*4096 + s*128 + gc*4);
    u16x4 o;
    o.x = f2bf(v.x); o.y = f2bf(v.y); o.z = f2bf(v.z); o.w = f2bf(v.w);
    const int chunk = (gc >> 1) ^ (row & 7);
    *(u16x4*)&Asw[row*128 + chunk*8 + (gc & 1)*4] = o;
  }
  // stage B: granule g: row=g>>4, ch=g&15 (u16x8). Coalesced 16B/lane.
  const u16* rsrc = rotb + (size_t)s*16384;
  #pragma unroll
  for (int p = 0; p < 8; ++p) {
    const int g = p*256 + t;
    const int row = g >> 4, ch = g & 15;
    u16x8 v = *(const u16x8*)(rsrc + row*128 + ch*8);
    *(u16x8*)&Bsw[row*128 + ((ch ^ (row & 7))*8)] = v;
  }
  __syncthreads();
  const int w = t >> 6, l = t & 63;
  const int fr = l & 15, fq = l >> 4;
  const int wm = (w >> 1)*64, wn = (w & 1)*64;
  f32x4 acc[4][4] = {};
  #pragma unroll
  for (int ks = 0; ks < 4; ++ks) {
    bf16x8 af[4], bfr[4];
    #pragma unroll
    for (int m = 0; m < 4; ++m)
      af[m] = *(const bf16x8*)&Asw[(wm + m*16 + fr)*128 + (((ks*4 + fq) ^ (fr & 7))*8)];
    #pragma unroll
    for (int n = 0; n < 4; ++n)
      bfr[n] = *(const bf16x8*)&Bsw[(wn + n*16 + fr)*128 + (((ks*4 + fq) ^ (fr & 7))*8)];
    #pragma unroll
    for (int m = 0; m < 4; ++m)
      #pragma unroll
      for (int n = 0; n < 4; ++n)
        acc[m][n] = __builtin_amdgcn_mfma_f32_16x16x32_bf16(
            af[m], bfr[n], acc[m][n], 0, 0, 0);
  }
  // epilogue: C/D col = fr (output col), row = fq*4 + reg; scale by boft_s
  #pragma unroll
  for (int m = 0; m < 4; ++m) {
    #pragma unroll
    for (int r = 0; r < 4; ++r) {
      const int row = rt*128 + wm + m*16 + fq*4 + r;
      const float sc = sscale[row];
      #pragma unroll
      for (int n = 0; n < 4; ++n) {
        const int col = s*128 + wn + n*16 + fr;
        SW[(size_t)row*4096 + col] = f2bf(acc[m][n][r] * sc);
      }
    }
  }
}

// ---------------- Kernel 4: x f32 -> bf16 (grid-stride, 2048 blocks) -------
__global__ __launch_bounds__(256) void cvt_kernel(
    const float* __restrict__ x, u16* __restrict__ xb) {
  #pragma unroll
  for (int rep = 0; rep < 4; ++rep) {
    const size_t i = (size_t)(rep*2048 + blockIdx.x) * 256 + threadIdx.x;
    const float4* p = (const float4*)x + i*2;
    float4 a = p[0], b = p[1];
    u16x8 o;
    o[0] = f2bf(a.x); o[1] = f2bf(a.y); o[2] = f2bf(a.z); o[3] = f2bf(a.w);
    o[4] = f2bf(b.x); o[5] = f2bf(b.y); o[6] = f2bf(b.z); o[7] = f2bf(b.w);
    *(u16x8*)(xb + i*8) = o;
  }
}

// ---------------- Kernel 5: bf16 MFMA GEMM — 32x32x16 shape ----------------
// R15: schedule family exhausted at ~45% (R8-R14: 42-46%). New lever:
// instruction shape. 32x32x16 bf16 runs ~15% faster per FLOP (m119: 2495 vs
// 2176 TF) and HALVES the MFMA count (32/wave/tile, 16-reg acc). Per wave:
// 4 M-tiles x 2 N-tiles of 32x32, 4 ks-steps of K=16. Same 3-bit XOR swizzle
// (quarter-wave check: fq5 fixed, l&7 sweeps 8 cols -> conflict-free). R13
// tail-read schedule kept (slot ping-pong: ks0/ks2 -> slot0, ks1/ks3 ->
// slot1). C/D: col=lane&31, row=(reg&3)+8*(reg>>2)+4*(lane>>5) [m74/m101].
#define GLDS16(g, l)                                                   \
  __builtin_amdgcn_global_load_lds(                                    \
      (const __attribute__((address_space(1))) void*)(g),              \
      (__attribute__((address_space(3))) void*)(l), 16, 0, 0)

__device__ __forceinline__ void bar() {
  asm volatile("" ::: "memory");
  __builtin_amdgcn_s_barrier();
  asm volatile("" ::: "memory");
}

__global__ __launch_bounds__(512, 2) void gemm_kernel(
    const u16* __restrict__ A, const u16* __restrict__ B,
    const float* __restrict__ bias, float* __restrict__ C) {
  constexpr int K = 4096, N = 4096, NT = 64;   // K-tiles of BK=64
  __shared__ u16 As[2*256*64];                 // [buf][256 rows][64 cols]
  __shared__ u16 Bs[2*256*64];
  const int t = threadIdx.x;
  const int w = t >> 6, l = t & 63;
  const int wr = w >> 2, wc = w & 3;            // wave -> (2 x 4) grid
  const int l31 = l & 31, fq5 = l >> 5, r7 = l & 7;

  // XCD-aware swizzle (nwg=256, %8==0 -> simple bijective form)
  const int wg  = blockIdx.x;
  const int swz = (wg & 7) * 32 + (wg >> 3);
  const int m0  = (swz & 15) * 256, n0 = (swz >> 4) * 256;

  // staging: thread t fills LDS-linear granule (row = w*8 + (l>>3), c = l&7);
  // that slot must hold logical col (l&7) ^ (row&7)  [row&7 = (l>>3)&7].
  const int grow = w*8 + (l >> 3);                       // + o*64 + half*128
  const int gcol = ((l & 7) ^ ((l >> 3) & 7)) * 8;
  const u16* aS = A + (size_t)(m0 + grow) * K + gcol;
  const u16* bS = B + (size_t)(n0 + grow) * K + gcol;
  const int wLds = w * 512;                               // u16, wave-uniform

  // frag read: row = base + (l&31); logical chunk = ks*2 + fq5;
  // stored chunk = logical ^ (row&7) = logical ^ (l&7)
  const u16* aRd = As + (wr*128 + l31)*64;
  const u16* bRd = Bs + (wc*64  + l31)*64;

  auto stgA = [&](int buf, int half, int o, int kt_) {
    GLDS16(aS + (size_t)(half*128 + o*64) * K + (size_t)kt_*64,
           As + buf*16384 + half*8192 + o*4096 + wLds);
  };
  auto stgB = [&](int buf, int half, int o, int kt_) {
    GLDS16(bS + (size_t)(half*128 + o*64) * K + (size_t)kt_*64,
           Bs + buf*16384 + half*8192 + o*4096 + wLds);
  };

  f32x16 acc[4][2] = {};         // [mt][nt], 16 f32 each (static idx only)
  bf16x8 aF[4][2], bF[2][2];     // [mt|nt][slot]; slot = ks & 1

  auto rdA = [&](int buf, int ks, int slot) {
    const u16* aC = aRd + buf*16384;
    const int off = ((ks*2 + fq5) ^ r7) * 8;
    #pragma unroll
    for (int mt = 0; mt < 4; ++mt)
      aF[mt][slot] = *(const bf16x8*)(aC + mt*2048 + off);
  };
  auto rdB = [&](int buf, int ks, int slot) {
    const u16* bC = bRd + buf*16384;
    const int off = ((ks*2 + fq5) ^ r7) * 8;
    #pragma unroll
    for (int nt = 0; nt < 2; ++nt)
      bF[nt][slot] = *(const bf16x8*)(bC + nt*2048 + off);
  };
  auto mmaKS = [&](int slot) {   // 8 MFMA, all independent within the burst
    __builtin_amdgcn_s_setprio(1);
    #pragma unroll
    for (int mt = 0; mt < 4; ++mt)
      #pragma unroll
      for (int nt = 0; nt < 2; ++nt)
        acc[mt][nt] = __builtin_amdgcn_mfma_f32_32x32x16_bf16(
            aF[mt][slot], bF[nt][slot], acc[mt][nt], 0, 0, 0);
    __builtin_amdgcn_s_setprio(0);
  };

  // prologue: tile0 -> buf0, tile1 -> buf1 (B then A per tile, 16 gloads)
  stgB(0,0,0,0); stgB(0,0,1,0); stgB(0,1,0,0); stgB(0,1,1,0);
  stgA(0,0,0,0); stgA(0,0,1,0); stgA(0,1,0,0); stgA(0,1,1,0);
  stgB(1,0,0,1); stgB(1,0,1,1); stgB(1,1,0,1); stgB(1,1,1,1);
  stgA(1,0,0,1); stgA(1,0,1,1); stgA(1,1,0,1); stgA(1,1,1,1);
  asm volatile("s_waitcnt vmcnt(8)" ::: "memory");   // t0 landed, t1 in flight
  bar();
  rdA(0, 0, 0); rdB(0, 0, 0);    // pre-read t0 ks0
  rdA(0, 1, 1); rdB(0, 1, 1);    // pre-read t0 ks1

  for (int kt = 0; kt < NT; ++kt) {
    const int cur = kt & 1;
    // ---- Φ0: mma ks0 ; tail: rd ks2 -> slot0 ----
    mmaKS(0);
    rdA(cur, 2, 0); rdB(cur, 2, 0);
    // ---- Φ1: mma ks1 ; tail: rd ks3 -> slot1 ; BAR ----
    mmaKS(1);
    rdA(cur, 3, 1); rdB(cur, 3, 1);
    bar();
    // ---- Φ2: stgB(kt+2) 2+2 around mma ks2 ; vmcnt ; BAR ----
    if (kt + 2 < NT) { stgB(cur,0,0,kt+2); stgB(cur,0,1,kt+2); }
    mmaKS(0);
    if (kt + 2 < NT) { stgB(cur,1,0,kt+2); stgB(cur,1,1,kt+2); }
    if (kt < NT - 2) {
      asm volatile("s_waitcnt vmcnt(4)" ::: "memory");   // tile kt+1 landed
    } else if (kt == NT - 2) {
      asm volatile("s_waitcnt vmcnt(0)" ::: "memory");
    }
    bar();
    // ---- Φ3: stgA(kt+2) 2+2 around mma ks3 ; tail: rd kt+1 ks0/ks1 ----
    if (kt + 2 < NT) { stgA(cur,0,0,kt+2); stgA(cur,0,1,kt+2); }
    mmaKS(1);
    if (kt + 2 < NT) { stgA(cur,1,0,kt+2); stgA(cur,1,1,kt+2); }
    if (kt + 1 < NT) {
      rdA(cur ^ 1, 0, 0); rdB(cur ^ 1, 0, 0);
      rdA(cur ^ 1, 1, 1); rdB(cur ^ 1, 1, 1);
    }
  }

  // epilogue: C/D col = lane&31, row = (r&3) + 8*(r>>2) + 4*fq5  [m74/m101]
  #pragma unroll
  for (int nt = 0; nt < 2; ++nt) {
    const int col = n0 + wc*64 + nt*32 + l31;
    const float bv = bias[col];
    #pragma unroll
    for (int mt = 0; mt < 4; ++mt) {
      const int rowb = m0 + wr*128 + mt*32 + 4*fq5;
      #pragma unroll
      for (int r = 0; r < 16; ++r) {
        const int row = rowb + (r & 3) + 8*(r >> 2);
        C[(size_t)row*N + col] = acc[mt][nt][r] + bv;
      }
    }
  }
}

extern "C" void kernel_launch(void* const* d_in, const int* in_sizes, int n_in,
                              void* d_out, int out_size, void* d_ws, size_t ws_size,
                              hipStream_t stream) {
  const float* x      = (const float*)d_in[0];   // (2,2048,4096)
  const float* W      = (const float*)d_in[1];   // (4096,4096)
  const float* bias   = (const float*)d_in[2];   // (4096)
  const float* boft_R = (const float*)d_in[3];   // (2,64,64,64)
  const float* boft_s = (const float*)d_in[4];   // (4096,1)
  float* out = (float*)d_out;

  char* ws = (char*)d_ws;
  float* Q    = (float*)ws;                        //  2 MB (128*64*64 f32)
  u16*   rotb = (u16*)  (ws + ((size_t)2  << 20)); //  1 MB (32*128*128 bf16)
  u16*   xb   = (u16*)  (ws + ((size_t)4  << 20)); // 32 MB
  u16*   swb  = (u16*)  (ws + ((size_t)36 << 20)); // 32 MB

  cayley_kernel  <<<128, 256, 0, stream>>>(boft_R, Q);
  rotbuild_kernel<<<32, 256, 0, stream>>>(Q, rotb);
  wtrans_kernel  <<<dim3(32, 32), 256, 0, stream>>>(W, rotb, boft_s, swb);
  cvt_kernel     <<<2048, 256, 0, stream>>>(x, xb);
  gemm_kernel    <<<256, 512, 0, stream>>>(xb, swb, bias, out);
}

// Round 16
// 183.880 us; speedup vs baseline: 1.1169x; 1.1169x over previous
//
#include <hip/hip_runtime.h>

typedef unsigned short u16;
typedef unsigned int   u32;
typedef __attribute__((ext_vector_type(4))) float f32x4;
typedef __attribute__((ext_vector_type(8))) short bf16x8;
typedef __attribute__((ext_vector_type(4))) unsigned short u16x4;
typedef __attribute__((ext_vector_type(8))) unsigned short u16x8;

__device__ __forceinline__ u16 f2bf(float f) {
  union { float f; u32 u; } v; v.f = f;
  u32 r = v.u + 0x7FFFu + ((v.u >> 16) & 1u);   // round-to-nearest-even
  return (u16)(r >> 16);
}

__device__ __forceinline__ float bcast(float v, int l) {
  return __uint_as_float(__builtin_amdgcn_readlane(__float_as_uint(v), l));
}

// ---------------- Kernel 1: Cayley Q = 2*(I+S)^-1 - I, S = 0.5(R - R^T) ----
__global__ __launch_bounds__(256, 1) void cayley_kernel(
    const float* __restrict__ R, float* __restrict__ Q) {
  const int b  = blockIdx.x;
  const int t  = threadIdx.x;
  const int j  = t & 63;                // column owner (lane)
  const int iw = t >> 6;                // wave = row-block owner
  __shared__ float Rl[64][65];          // staged R (padded: transpose-read free)
  __shared__ float prow[2][2][64];      // [k parity][A|B][j]
  const float* Rb = R + (size_t)b * 4096;
  for (int idx = t; idx < 4096; idx += 256)
    Rl[idx >> 6][idx & 63] = Rb[idx];
  __syncthreads();
  float Ac[16], Bc[16];                 // A[16iw+i'][j], B[16iw+i'][j]
  #pragma unroll
  for (int i2 = 0; i2 < 16; ++i2) {
    const int i = iw*16 + i2;
    float s = 0.5f * (Rl[i][j] - Rl[j][i]);
    Ac[i2] = (i == j) ? (1.0f + s) : s;
    Bc[i2] = (i == j) ? 1.0f : 0.0f;
  }
  __syncthreads();
  #pragma unroll
  for (int kb = 0; kb < 4; ++kb) {
    #pragma unroll
    for (int kp = 0; kp < 16; ++kp) {
      const int k = kb*16 + kp;         // compile-time constant
      if (iw == kb) {                   // wave-uniform: pivot wave scales row k
        float pinv = 1.0f / bcast(Ac[kp], k);
        float ar = Ac[kp] * pinv;
        float br = Bc[kp] * pinv;
        Ac[kp] = ar; Bc[kp] = br;
        prow[k & 1][0][j] = ar;
        prow[k & 1][1][j] = br;
      }
      __syncthreads();
      const float ar = prow[k & 1][0][j];
      const float br = prow[k & 1][1][j];
      #pragma unroll
      for (int i2 = 0; i2 < 16; ++i2) { // eliminate own rows (static idx)
        float f = bcast(Ac[i2], k);     // A[16iw+i2][k], pre-update (lockstep)
        if (iw == kb && i2 == kp) f = 0.0f;   // pivot row preserved
        Ac[i2] -= f * ar;
        Bc[i2] -= f * br;
      }
    }
  }
  float* Qb = Q + (size_t)b * 4096;
  #pragma unroll
  for (int i2 = 0; i2 < 16; ++i2) {
    const int i = iw*16 + i2;
    Qb[i*64 + j] = 2.0f * Bc[i2] - ((i == j) ? 1.0f : 0.0f);
  }
}

// ---------------- Kernel 2: rot superblocks -> bf16 (R16: 4x split) --------
// grid (32 s, 4 q): block computes cc window [q*16, q*16+16) for all 128 a.
// 256 thr: a_l = t&31 + 32*row-group? No: a handled by (t&31) + dh=(t>>5)&1,
// cq = t>>6 covers cc quarters -> all 256 threads busy, 512 FMA/thread.
__global__ __launch_bounds__(256) void rotbuild_kernel(
    const float* __restrict__ Q, u16* __restrict__ rotb) {
  const int s = blockIdx.x;
  const int aq = blockIdx.y;            // a-quarter 0..3 (32 a-rows each)
  const int t = threadIdx.x;
  __shared__ float Q1l[2][64][65];      // padded
  __shared__ f32x4 Q0l[2][64][16];      // [dh][k][c4]
  const float* Q0g = Q + (size_t)(2*s) * 4096;        // factor 0: blocks 2s,2s+1
  const float* Q1g = Q + (size_t)(64 + 2*s) * 4096;   // factor 1 starts at block 64
  for (int i = t; i < 2*4096; i += 256) {
    int e = i >> 12, r = (i >> 6) & 63, c = i & 63;
    Q1l[e][r][c] = Q1g[i];
    ((float*)&Q0l[e][r][0])[c] = Q0g[i];
  }
  __syncthreads();
  const int a_l = aq*32 + (t & 31);     // a-row this thread serves
  const int dh  = (t >> 5) & 1;         // c-half
  const int cq  = t >> 6;               // c-quarter within half (4 granules)
  const int g   = a_l >> 5;             // local butterfly perm (involution)
  const int pa  = a_l + ((g == 1) ? 32 : (g == 2) ? -32 : 0);
  const int e = pa >> 6, pa64 = pa & 63;
  float q1v[32];
  #pragma unroll
  for (int jj = 0; jj < 32; ++jj) q1v[jj] = Q1l[e][pa64][dh*32 + jj];
  f32x4 acc4[4] = {};
  #pragma unroll
  for (int jj = 0; jj < 32; ++jj) {
    #pragma unroll
    for (int c4 = 0; c4 < 4; ++c4)
      acc4[c4] += q1v[jj] * Q0l[dh][e*32 + jj][cq*4 + c4];  // broadcast read
  }
  u16* dst = rotb + (size_t)s*16384 + (size_t)a_l*128 + dh*64 + cq*16;
  #pragma unroll
  for (int c4 = 0; c4 < 4; ++c4) {
    u16x4 o;
    o.x = f2bf(acc4[c4].x); o.y = f2bf(acc4[c4].y);
    o.z = f2bf(acc4[c4].z); o.w = f2bf(acc4[c4].w);
    *(u16x4*)&dst[c4*4] = o;
  }
}

// ---------------- Kernel 3: SW = (W @ rot^T) * s -> bf16, MFMA -------------
__global__ __launch_bounds__(256) void wtrans_kernel(
    const float* __restrict__ W, const u16* __restrict__ rotb,
    const float* __restrict__ sscale, u16* __restrict__ SW) {
  const int rt = blockIdx.x;            // row tile 0..31
  const int s  = blockIdx.y;            // superblock 0..31
  const int t  = threadIdx.x;
  __shared__ u16 Asw[128*128];          // W tile bf16, swizzled
  __shared__ u16 Bsw[128*128];          // rot_s bf16, swizzled
  // stage A: granule g: row=g>>5, gc=g&31 (f32x4). Coalesced 16B/lane.
  #pragma unroll
  for (int p = 0; p < 16; ++p) {
    const int g = p*256 + t;
    const int row = g >> 5, gc = g & 31;
    float4 v = *(const float4*)(W + (size_t)(rt*128 + row)*4096 + s*128 + gc*4);
    u16x4 o;
    o.x = f2bf(v.x); o.y = f2bf(v.y); o.z = f2bf(v.z); o.w = f2bf(v.w);
    const int chunk = (gc >> 1) ^ (row & 7);
    *(u16x4*)&Asw[row*128 + chunk*8 + (gc & 1)*4] = o;
  }
  // stage B: granule g: row=g>>4, ch=g&15 (u16x8). Coalesced 16B/lane.
  const u16* rsrc = rotb + (size_t)s*16384;
  #pragma unroll
  for (int p = 0; p < 8; ++p) {
    const int g = p*256 + t;
    const int row = g >> 4, ch = g & 15;
    u16x8 v = *(const u16x8*)(rsrc + row*128 + ch*8);
    *(u16x8*)&Bsw[row*128 + ((ch ^ (row & 7))*8)] = v;
  }
  __syncthreads();
  const int w = t >> 6, l = t & 63;
  const int fr = l & 15, fq = l >> 4;
  const int wm = (w >> 1)*64, wn = (w & 1)*64;
  f32x4 acc[4][4] = {};
  #pragma unroll
  for (int ks = 0; ks < 4; ++ks) {
    bf16x8 af[4], bfr[4];
    #pragma unroll
    for (int m = 0; m < 4; ++m)
      af[m] = *(const bf16x8*)&Asw[(wm + m*16 + fr)*128 + (((ks*4 + fq) ^ (fr & 7))*8)];
    #pragma unroll
    for (int n = 0; n < 4; ++n)
      bfr[n] = *(const bf16x8*)&Bsw[(wn + n*16 + fr)*128 + (((ks*4 + fq) ^ (fr & 7))*8)];
    #pragma unroll
    for (int m = 0; m < 4; ++m)
      #pragma unroll
      for (int n = 0; n < 4; ++n)
        acc[m][n] = __builtin_amdgcn_mfma_f32_16x16x32_bf16(
            af[m], bfr[n], acc[m][n], 0, 0, 0);
  }
  // epilogue: C/D col = fr (output col), row = fq*4 + reg; scale by boft_s
  #pragma unroll
  for (int m = 0; m < 4; ++m) {
    #pragma unroll
    for (int r = 0; r < 4; ++r) {
      const int row = rt*128 + wm + m*16 + fq*4 + r;
      const float sc = sscale[row];
      #pragma unroll
      for (int n = 0; n < 4; ++n) {
        const int col = s*128 + wn + n*16 + fr;
        SW[(size_t)row*4096 + col] = f2bf(acc[m][n][r] * sc);
      }
    }
  }
}

// ---------------- Kernel 4: x f32 -> bf16 (grid-stride, 2048 blocks) -------
__global__ __launch_bounds__(256) void cvt_kernel(
    const float* __restrict__ x, u16* __restrict__ xb) {
  #pragma unroll
  for (int rep = 0; rep < 4; ++rep) {
    const size_t i = (size_t)(rep*2048 + blockIdx.x) * 256 + threadIdx.x;
    const float4* p = (const float4*)x + i*2;
    float4 a = p[0], b = p[1];
    u16x8 o;
    o[0] = f2bf(a.x); o[1] = f2bf(a.y); o[2] = f2bf(a.z); o[3] = f2bf(a.w);
    o[4] = f2bf(b.x); o[5] = f2bf(b.y); o[6] = f2bf(b.z); o[7] = f2bf(b.w);
    *(u16x8*)(xb + i*8) = o;
  }
}

// ---------------- Kernel 5: bf16 MFMA GEMM — R14 config (best measured) ----
// R16: REVERTED to R14 exactly (128.2 us, MfmaUtil 45.9%, conflicts 0).
// R15's 32x32x16 shape regressed (142 us, conflicts back at 1.26e7) with a
// bank pattern my quarter-wave model says is free — model incomplete; the
// shape also dropped VGPR 120->104 (AGPR pressure, likely read splitting).
// Schedule family (R8-R14) brackets 42-46% util; marginal edits move <=2%.
#define GLDS16(g, l)                                                   \
  __builtin_amdgcn_global_load_lds(                                    \
      (const __attribute__((address_space(1))) void*)(g),              \
      (__attribute__((address_space(3))) void*)(l), 16, 0, 0)

__device__ __forceinline__ void bar() {
  asm volatile("" ::: "memory");
  __builtin_amdgcn_s_barrier();
  asm volatile("" ::: "memory");
}

__global__ __launch_bounds__(512, 2) void gemm_kernel(
    const u16* __restrict__ A, const u16* __restrict__ B,
    const float* __restrict__ bias, float* __restrict__ C) {
  constexpr int K = 4096, N = 4096, NT = 64;   // K-tiles of BK=64
  __shared__ u16 As[2*256*64];                 // [buf][256 rows][64 cols]
  __shared__ u16 Bs[2*256*64];
  const int t = threadIdx.x;
  const int w = t >> 6, l = t & 63;
  const int wr = w >> 2, wc = w & 3;            // wave -> (2 x 4) grid
  const int fr = l & 15, fq = l >> 4;

  // XCD-aware swizzle (nwg=256, %8==0 -> simple bijective form)
  const int wg  = blockIdx.x;
  const int swz = (wg & 7) * 32 + (wg >> 3);
  const int m0  = (swz & 15) * 256, n0 = (swz >> 4) * 256;

  // staging: thread t fills LDS-linear granule (row = w*8 + (l>>3), c = l&7);
  // that slot must hold logical col (l&7) ^ (row&7)  [row&7 = (l>>3)&7].
  const int grow = w*8 + (l >> 3);                       // + o*64 + half*128
  const int gcol = ((l & 7) ^ ((l >> 3) & 7)) * 8;
  const u16* aS = A + (size_t)(m0 + grow) * K + gcol;
  const u16* bS = B + (size_t)(n0 + grow) * K + gcol;
  const int wLds = w * 512;                               // u16, wave-uniform

  // read: logical col = fq + 4*ks; stored col = (fq ^ (fr&7)) ^ 4*ks
  const int colbase = (fq ^ (fr & 7)) * 8;                // u16; ks flips ^32
  const u16* aRd = As + (wr*128 + fr)*64;
  const u16* bRd = Bs + (wc*64  + fr)*64;

  auto stgA = [&](int buf, int half, int o, int kt_) {
    GLDS16(aS + (size_t)(half*128 + o*64) * K + (size_t)kt_*64,
           As + buf*16384 + half*8192 + o*4096 + wLds);
  };
  auto stgB = [&](int buf, int half, int o, int kt_) {
    GLDS16(bS + (size_t)(half*128 + o*64) * K + (size_t)kt_*64,
           Bs + buf*16384 + half*8192 + o*4096 + wLds);
  };

  f32x4 acc[8][4] = {};
  bf16x8 aF[4][2], bF[4][2];   // aF: A0 then A1; bF[0..1]=B0, bF[2..3]=B1

  auto rdA = [&](int buf, int mh) {
    const u16* aC = aRd + buf*16384;
    #pragma unroll
    for (int m = 0; m < 4; ++m) {
      aF[m][0] = *(const bf16x8*)(aC + (mh*4 + m)*1024 + colbase);
      aF[m][1] = *(const bf16x8*)(aC + (mh*4 + m)*1024 + (colbase ^ 32));
    }
  };
  auto rdB = [&](int buf, int nh) {
    const u16* bC = bRd + buf*16384;
    #pragma unroll
    for (int n = 0; n < 2; ++n) {
      bF[nh*2 + n][0] = *(const bf16x8*)(bC + (nh*2 + n)*1024 + colbase);
      bF[nh*2 + n][1] = *(const bf16x8*)(bC + (nh*2 + n)*1024 + (colbase ^ 32));
    }
  };
  // ks-OUTER: 8 independent MFMAs, then 8 partners (dep distance = 8)
  auto mma = [&](int mh, int nh) {
    __builtin_amdgcn_s_setprio(1);
    #pragma unroll
    for (int ks = 0; ks < 2; ++ks)
      #pragma unroll
      for (int m = 0; m < 4; ++m)
        #pragma unroll
        for (int n = 0; n < 2; ++n)
          acc[mh*4 + m][nh*2 + n] = __builtin_amdgcn_mfma_f32_16x16x32_bf16(
              aF[m][ks], bF[nh*2 + n][ks], acc[mh*4 + m][nh*2 + n], 0, 0, 0);
    __builtin_amdgcn_s_setprio(0);
  };

  // prologue: tile0 -> buf0, tile1 -> buf1 (B then A per tile, 16 gloads)
  stgB(0,0,0,0); stgB(0,0,1,0); stgB(0,1,0,0); stgB(0,1,1,0);
  stgA(0,0,0,0); stgA(0,0,1,0); stgA(0,1,0,0); stgA(0,1,1,0);
  stgB(1,0,0,1); stgB(1,0,1,1); stgB(1,1,0,1); stgB(1,1,1,1);
  stgA(1,0,0,1); stgA(1,0,1,1); stgA(1,1,0,1); stgA(1,1,1,1);
  asm volatile("s_waitcnt vmcnt(8)" ::: "memory");   // t0 landed, t1 in flight
  bar();
  rdA(0, 0); rdB(0, 0);                               // pre-read t0 A0,B0

  for (int kt = 0; kt < NT; ++kt) {
    const int cur = kt & 1;
    // ---- Φ0: mma(0,0) ; tail: rd B1(cur) ----
    mma(0, 0);
    rdB(cur, 1);
    // ---- Φ1: mma(0,1) ; tail: rd A1(cur) ; BAR ----
    mma(0, 1);
    rdA(cur, 1);
    bar();
    // ---- Φ2: stgB(kt+2) 2+2 around mma(1,1) ; vmcnt ; BAR ----
    if (kt + 2 < NT) { stgB(cur,0,0,kt+2); stgB(cur,0,1,kt+2); }
    mma(1, 1);
    if (kt + 2 < NT) { stgB(cur,1,0,kt+2); stgB(cur,1,1,kt+2); }
    if (kt < NT - 2) {
      asm volatile("s_waitcnt vmcnt(4)" ::: "memory");   // tile kt+1 landed
    } else if (kt == NT - 2) {
      asm volatile("s_waitcnt vmcnt(0)" ::: "memory");
    }
    bar();
    // ---- Φ3: stgA(kt+2) 2+2 around mma(1,0) ; tail: rd A0,B0(kt+1) ----
    if (kt + 2 < NT) { stgA(cur,0,0,kt+2); stgA(cur,0,1,kt+2); }
    mma(1, 0);
    if (kt + 2 < NT) { stgA(cur,1,0,kt+2); stgA(cur,1,1,kt+2); }
    if (kt + 1 < NT) { rdA(cur ^ 1, 0); rdB(cur ^ 1, 0); }
  }

  // epilogue: C/D layout col = lane&15 (fr), row = fq*4 + reg
  #pragma unroll
  for (int nf = 0; nf < 4; ++nf) {
    const int col = n0 + wc*64 + nf*16 + fr;
    const float bv = bias[col];
    #pragma unroll
    for (int mf = 0; mf < 8; ++mf) {
      const int rowb = m0 + wr*128 + mf*16 + fq*4;
      #pragma unroll
      for (int r = 0; r < 4; ++r)
        C[(size_t)(rowb + r)*N + col] = acc[mf][nf][r] + bv;
    }
  }
}

extern "C" void kernel_launch(void* const* d_in, const int* in_sizes, int n_in,
                              void* d_out, int out_size, void* d_ws, size_t ws_size,
                              hipStream_t stream) {
  const float* x      = (const float*)d_in[0];   // (2,2048,4096)
  const float* W      = (const float*)d_in[1];   // (4096,4096)
  const float* bias   = (const float*)d_in[2];   // (4096)
  const float* boft_R = (const float*)d_in[3];   // (2,64,64,64)
  const float* boft_s = (const float*)d_in[4];   // (4096,1)
  float* out = (float*)d_out;

  char* ws = (char*)d_ws;
  float* Q    = (float*)ws;                        //  2 MB (128*64*64 f32)
  u16*   rotb = (u16*)  (ws + ((size_t)2  << 20)); //  1 MB (32*128*128 bf16)
  u16*   xb   = (u16*)  (ws + ((size_t)4  << 20)); // 32 MB
  u16*   swb  = (u16*)  (ws + ((size_t)36 << 20)); // 32 MB

  cayley_kernel  <<<128, 256, 0, stream>>>(boft_R, Q);
  rotbuild_kernel<<<dim3(32, 4), 256, 0, stream>>>(Q, rotb);
  wtrans_kernel  <<<dim3(32, 32), 256, 0, stream>>>(W, rotb, boft_s, swb);
  cvt_kernel     <<<2048, 256, 0, stream>>>(x, xb);
  gemm_kernel    <<<256, 512, 0, stream>>>(xb, swb, bias, out);
}

// Round 17
// 178.221 us; speedup vs baseline: 1.1523x; 1.0318x over previous
//
#include <hip/hip_runtime.h>

typedef unsigned short u16;
typedef unsigned int   u32;
typedef __attribute__((ext_vector_type(4))) float f32x4;
typedef __attribute__((ext_vector_type(8))) short bf16x8;
typedef __attribute__((ext_vector_type(4))) unsigned short u16x4;
typedef __attribute__((ext_vector_type(8))) unsigned short u16x8;

__device__ __forceinline__ u16 f2bf(float f) {
  union { float f; u32 u; } v; v.f = f;
  u32 r = v.u + 0x7FFFu + ((v.u >> 16) & 1u);   // round-to-nearest-even
  return (u16)(r >> 16);
}

__device__ __forceinline__ float bcast(float v, int l) {
  return __uint_as_float(__builtin_amdgcn_readlane(__float_as_uint(v), l));
}

// ---------------- Kernel 1: Cayley Q = 2*(I+S)^-1 - I, S = 0.5(R - R^T) ----
__global__ __launch_bounds__(256, 1) void cayley_kernel(
    const float* __restrict__ R, float* __restrict__ Q) {
  const int b  = blockIdx.x;
  const int t  = threadIdx.x;
  const int j  = t & 63;                // column owner (lane)
  const int iw = t >> 6;                // wave = row-block owner
  __shared__ float Rl[64][65];          // staged R (padded: transpose-read free)
  __shared__ float prow[2][2][64];      // [k parity][A|B][j]
  const float* Rb = R + (size_t)b * 4096;
  for (int idx = t; idx < 4096; idx += 256)
    Rl[idx >> 6][idx & 63] = Rb[idx];
  __syncthreads();
  float Ac[16], Bc[16];                 // A[16iw+i'][j], B[16iw+i'][j]
  #pragma unroll
  for (int i2 = 0; i2 < 16; ++i2) {
    const int i = iw*16 + i2;
    float s = 0.5f * (Rl[i][j] - Rl[j][i]);
    Ac[i2] = (i == j) ? (1.0f + s) : s;
    Bc[i2] = (i == j) ? 1.0f : 0.0f;
  }
  __syncthreads();
  #pragma unroll
  for (int kb = 0; kb < 4; ++kb) {
    #pragma unroll
    for (int kp = 0; kp < 16; ++kp) {
      const int k = kb*16 + kp;         // compile-time constant
      if (iw == kb) {                   // wave-uniform: pivot wave scales row k
        float pinv = 1.0f / bcast(Ac[kp], k);
        float ar = Ac[kp] * pinv;
        float br = Bc[kp] * pinv;
        Ac[kp] = ar; Bc[kp] = br;
        prow[k & 1][0][j] = ar;
        prow[k & 1][1][j] = br;
      }
      __syncthreads();
      const float ar = prow[k & 1][0][j];
      const float br = prow[k & 1][1][j];
      #pragma unroll
      for (int i2 = 0; i2 < 16; ++i2) { // eliminate own rows (static idx)
        float f = bcast(Ac[i2], k);     // A[16iw+i2][k], pre-update (lockstep)
        if (iw == kb && i2 == kp) f = 0.0f;   // pivot row preserved
        Ac[i2] -= f * ar;
        Bc[i2] -= f * br;
      }
    }
  }
  float* Qb = Q + (size_t)b * 4096;
  #pragma unroll
  for (int i2 = 0; i2 < 16; ++i2) {
    const int i = iw*16 + i2;
    Qb[i*64 + j] = 2.0f * Bc[i2] - ((i == j) ? 1.0f : 0.0f);
  }
}

// ---------------- Kernel 2: rot superblocks -> bf16 (4x split) -------------
__global__ __launch_bounds__(256) void rotbuild_kernel(
    const float* __restrict__ Q, u16* __restrict__ rotb) {
  const int s = blockIdx.x;
  const int aq = blockIdx.y;            // a-quarter 0..3 (32 a-rows each)
  const int t = threadIdx.x;
  __shared__ float Q1l[2][64][65];      // padded
  __shared__ f32x4 Q0l[2][64][16];      // [dh][k][c4]
  const float* Q0g = Q + (size_t)(2*s) * 4096;        // factor 0: blocks 2s,2s+1
  const float* Q1g = Q + (size_t)(64 + 2*s) * 4096;   // factor 1 starts at block 64
  for (int i = t; i < 2*4096; i += 256) {
    int e = i >> 12, r = (i >> 6) & 63, c = i & 63;
    Q1l[e][r][c] = Q1g[i];
    ((float*)&Q0l[e][r][0])[c] = Q0g[i];
  }
  __syncthreads();
  const int a_l = aq*32 + (t & 31);     // a-row this thread serves
  const int dh  = (t >> 5) & 1;         // c-half
  const int cq  = t >> 6;               // c-quarter within half (4 granules)
  const int g   = a_l >> 5;             // local butterfly perm (involution)
  const int pa  = a_l + ((g == 1) ? 32 : (g == 2) ? -32 : 0);
  const int e = pa >> 6, pa64 = pa & 63;
  float q1v[32];
  #pragma unroll
  for (int jj = 0; jj < 32; ++jj) q1v[jj] = Q1l[e][pa64][dh*32 + jj];
  f32x4 acc4[4] = {};
  #pragma unroll
  for (int jj = 0; jj < 32; ++jj) {
    #pragma unroll
    for (int c4 = 0; c4 < 4; ++c4)
      acc4[c4] += q1v[jj] * Q0l[dh][e*32 + jj][cq*4 + c4];  // broadcast read
  }
  u16* dst = rotb + (size_t)s*16384 + (size_t)a_l*128 + dh*64 + cq*16;
  #pragma unroll
  for (int c4 = 0; c4 < 4; ++c4) {
    u16x4 o;
    o.x = f2bf(acc4[c4].x); o.y = f2bf(acc4[c4].y);
    o.z = f2bf(acc4[c4].z); o.w = f2bf(acc4[c4].w);
    *(u16x4*)&dst[c4*4] = o;
  }
}

// ---------------- Kernel 3: merged prep = wtrans (1024) + cvt (2048) -------
// R17: cvt has no dep on the transform chain; merged with mod-3 block
// interleave so BW-bound cvt fills wtrans's MFMA/LDS phases. Serial cost
// ~40us; combined-traffic floor 192MB/6.3TBs ~= 30us.
__global__ __launch_bounds__(256) void prep_kernel(
    const float* __restrict__ W, const u16* __restrict__ rotb,
    const float* __restrict__ sscale, u16* __restrict__ SW,
    const float* __restrict__ x, u16* __restrict__ xb) {
  __shared__ u16 Asw[128*128];          // W tile bf16, swizzled
  __shared__ u16 Bsw[128*128];          // rot_s bf16, swizzled
  const int bid = blockIdx.x;
  const int t   = threadIdx.x;
  if (bid % 3 != 0) {
    // ---------------- cvt: x f32 -> bf16, 2048 blocks, 4 reps -------------
    const int c_id = bid - 1 - bid/3;   // 0..2047 (verified bijective)
    #pragma unroll
    for (int rep = 0; rep < 4; ++rep) {
      const size_t i = (size_t)(rep*2048 + c_id) * 256 + t;
      const float4* p = (const float4*)x + i*2;
      float4 a = p[0], b = p[1];
      u16x8 o;
      o[0] = f2bf(a.x); o[1] = f2bf(a.y); o[2] = f2bf(a.z); o[3] = f2bf(a.w);
      o[4] = f2bf(b.x); o[5] = f2bf(b.y); o[6] = f2bf(b.z); o[7] = f2bf(b.w);
      *(u16x8*)(xb + i*8) = o;
    }
    return;
  }
  // ---------------- wtrans: SW = (W @ rot^T) * s -> bf16, MFMA ------------
  const int w_id = bid / 3;             // 0..1023
  const int rt = w_id & 31;             // row tile
  const int s  = w_id >> 5;             // superblock
  // stage A: granule g: row=g>>5, gc=g&31 (f32x4). Coalesced 16B/lane.
  #pragma unroll
  for (int p = 0; p < 16; ++p) {
    const int g = p*256 + t;
    const int row = g >> 5, gc = g & 31;
    float4 v = *(const float4*)(W + (size_t)(rt*128 + row)*4096 + s*128 + gc*4);
    u16x4 o;
    o.x = f2bf(v.x); o.y = f2bf(v.y); o.z = f2bf(v.z); o.w = f2bf(v.w);
    const int chunk = (gc >> 1) ^ (row & 7);
    *(u16x4*)&Asw[row*128 + chunk*8 + (gc & 1)*4] = o;
  }
  // stage B: granule g: row=g>>4, ch=g&15 (u16x8). Coalesced 16B/lane.
  const u16* rsrc = rotb + (size_t)s*16384;
  #pragma unroll
  for (int p = 0; p < 8; ++p) {
    const int g = p*256 + t;
    const int row = g >> 4, ch = g & 15;
    u16x8 v = *(const u16x8*)(rsrc + row*128 + ch*8);
    *(u16x8*)&Bsw[row*128 + ((ch ^ (row & 7))*8)] = v;
  }
  __syncthreads();
  const int w = t >> 6, l = t & 63;
  const int fr = l & 15, fq = l >> 4;
  const int wm = (w >> 1)*64, wn = (w & 1)*64;
  f32x4 acc[4][4] = {};
  #pragma unroll
  for (int ks = 0; ks < 4; ++ks) {
    bf16x8 af[4], bfr[4];
    #pragma unroll
    for (int m = 0; m < 4; ++m)
      af[m] = *(const bf16x8*)&Asw[(wm + m*16 + fr)*128 + (((ks*4 + fq) ^ (fr & 7))*8)];
    #pragma unroll
    for (int n = 0; n < 4; ++n)
      bfr[n] = *(const bf16x8*)&Bsw[(wn + n*16 + fr)*128 + (((ks*4 + fq) ^ (fr & 7))*8)];
    #pragma unroll
    for (int m = 0; m < 4; ++m)
      #pragma unroll
      for (int n = 0; n < 4; ++n)
        acc[m][n] = __builtin_amdgcn_mfma_f32_16x16x32_bf16(
            af[m], bfr[n], acc[m][n], 0, 0, 0);
  }
  // epilogue: C/D col = fr (output col), row = fq*4 + reg; scale by boft_s
  #pragma unroll
  for (int m = 0; m < 4; ++m) {
    #pragma unroll
    for (int r = 0; r < 4; ++r) {
      const int row = rt*128 + wm + m*16 + fq*4 + r;
      const float sc = sscale[row];
      #pragma unroll
      for (int n = 0; n < 4; ++n) {
        const int col = s*128 + wn + n*16 + fr;
        SW[(size_t)row*4096 + col] = f2bf(acc[m][n][r] * sc);
      }
    }
  }
}

// ---------------- Kernel 5: bf16 MFMA GEMM — R14 config (best measured) ----
// 128.2-130.5 us, MfmaUtil ~46%, conflicts 0. Schedule family R8-R14
// bracketed 42-46%; frozen as final.
#define GLDS16(g, l)                                                   \
  __builtin_amdgcn_global_load_lds(                                    \
      (const __attribute__((address_space(1))) void*)(g),              \
      (__attribute__((address_space(3))) void*)(l), 16, 0, 0)

__device__ __forceinline__ void bar() {
  asm volatile("" ::: "memory");
  __builtin_amdgcn_s_barrier();
  asm volatile("" ::: "memory");
}

__global__ __launch_bounds__(512, 2) void gemm_kernel(
    const u16* __restrict__ A, const u16* __restrict__ B,
    const float* __restrict__ bias, float* __restrict__ C) {
  constexpr int K = 4096, N = 4096, NT = 64;   // K-tiles of BK=64
  __shared__ u16 As[2*256*64];                 // [buf][256 rows][64 cols]
  __shared__ u16 Bs[2*256*64];
  const int t = threadIdx.x;
  const int w = t >> 6, l = t & 63;
  const int wr = w >> 2, wc = w & 3;            // wave -> (2 x 4) grid
  const int fr = l & 15, fq = l >> 4;

  // XCD-aware swizzle (nwg=256, %8==0 -> simple bijective form)
  const int wg  = blockIdx.x;
  const int swz = (wg & 7) * 32 + (wg >> 3);
  const int m0  = (swz & 15) * 256, n0 = (swz >> 4) * 256;

  // staging: thread t fills LDS-linear granule (row = w*8 + (l>>3), c = l&7);
  // that slot must hold logical col (l&7) ^ (row&7)  [row&7 = (l>>3)&7].
  const int grow = w*8 + (l >> 3);                       // + o*64 + half*128
  const int gcol = ((l & 7) ^ ((l >> 3) & 7)) * 8;
  const u16* aS = A + (size_t)(m0 + grow) * K + gcol;
  const u16* bS = B + (size_t)(n0 + grow) * K + gcol;
  const int wLds = w * 512;                               // u16, wave-uniform

  // read: logical col = fq + 4*ks; stored col = (fq ^ (fr&7)) ^ 4*ks
  const int colbase = (fq ^ (fr & 7)) * 8;                // u16; ks flips ^32
  const u16* aRd = As + (wr*128 + fr)*64;
  const u16* bRd = Bs + (wc*64  + fr)*64;

  auto stgA = [&](int buf, int half, int o, int kt_) {
    GLDS16(aS + (size_t)(half*128 + o*64) * K + (size_t)kt_*64,
           As + buf*16384 + half*8192 + o*4096 + wLds);
  };
  auto stgB = [&](int buf, int half, int o, int kt_) {
    GLDS16(bS + (size_t)(half*128 + o*64) * K + (size_t)kt_*64,
           Bs + buf*16384 + half*8192 + o*4096 + wLds);
  };

  f32x4 acc[8][4] = {};
  bf16x8 aF[4][2], bF[4][2];   // aF: A0 then A1; bF[0..1]=B0, bF[2..3]=B1

  auto rdA = [&](int buf, int mh) {
    const u16* aC = aRd + buf*16384;
    #pragma unroll
    for (int m = 0; m < 4; ++m) {
      aF[m][0] = *(const bf16x8*)(aC + (mh*4 + m)*1024 + colbase);
      aF[m][1] = *(const bf16x8*)(aC + (mh*4 + m)*1024 + (colbase ^ 32));
    }
  };
  auto rdB = [&](int buf, int nh) {
    const u16* bC = bRd + buf*16384;
    #pragma unroll
    for (int n = 0; n < 2; ++n) {
      bF[nh*2 + n][0] = *(const bf16x8*)(bC + (nh*2 + n)*1024 + colbase);
      bF[nh*2 + n][1] = *(const bf16x8*)(bC + (nh*2 + n)*1024 + (colbase ^ 32));
    }
  };
  // ks-OUTER: 8 independent MFMAs, then 8 partners (dep distance = 8)
  auto mma = [&](int mh, int nh) {
    __builtin_amdgcn_s_setprio(1);
    #pragma unroll
    for (int ks = 0; ks < 2; ++ks)
      #pragma unroll
      for (int m = 0; m < 4; ++m)
        #pragma unroll
        for (int n = 0; n < 2; ++n)
          acc[mh*4 + m][nh*2 + n] = __builtin_amdgcn_mfma_f32_16x16x32_bf16(
              aF[m][ks], bF[nh*2 + n][ks], acc[mh*4 + m][nh*2 + n], 0, 0, 0);
    __builtin_amdgcn_s_setprio(0);
  };

  // prologue: tile0 -> buf0, tile1 -> buf1 (B then A per tile, 16 gloads)
  stgB(0,0,0,0); stgB(0,0,1,0); stgB(0,1,0,0); stgB(0,1,1,0);
  stgA(0,0,0,0); stgA(0,0,1,0); stgA(0,1,0,0); stgA(0,1,1,0);
  stgB(1,0,0,1); stgB(1,0,1,1); stgB(1,1,0,1); stgB(1,1,1,1);
  stgA(1,0,0,1); stgA(1,0,1,1); stgA(1,1,0,1); stgA(1,1,1,1);
  asm volatile("s_waitcnt vmcnt(8)" ::: "memory");   // t0 landed, t1 in flight
  bar();
  rdA(0, 0); rdB(0, 0);                               // pre-read t0 A0,B0

  for (int kt = 0; kt < NT; ++kt) {
    const int cur = kt & 1;
    // ---- Φ0: mma(0,0) ; tail: rd B1(cur) ----
    mma(0, 0);
    rdB(cur, 1);
    // ---- Φ1: mma(0,1) ; tail: rd A1(cur) ; BAR ----
    mma(0, 1);
    rdA(cur, 1);
    bar();
    // ---- Φ2: stgB(kt+2) 2+2 around mma(1,1) ; vmcnt ; BAR ----
    if (kt + 2 < NT) { stgB(cur,0,0,kt+2); stgB(cur,0,1,kt+2); }
    mma(1, 1);
    if (kt + 2 < NT) { stgB(cur,1,0,kt+2); stgB(cur,1,1,kt+2); }
    if (kt < NT - 2) {
      asm volatile("s_waitcnt vmcnt(4)" ::: "memory");   // tile kt+1 landed
    } else if (kt == NT - 2) {
      asm volatile("s_waitcnt vmcnt(0)" ::: "memory");
    }
    bar();
    // ---- Φ3: stgA(kt+2) 2+2 around mma(1,0) ; tail: rd A0,B0(kt+1) ----
    if (kt + 2 < NT) { stgA(cur,0,0,kt+2); stgA(cur,0,1,kt+2); }
    mma(1, 0);
    if (kt + 2 < NT) { stgA(cur,1,0,kt+2); stgA(cur,1,1,kt+2); }
    if (kt + 1 < NT) { rdA(cur ^ 1, 0); rdB(cur ^ 1, 0); }
  }

  // epilogue: C/D layout col = lane&15 (fr), row = fq*4 + reg
  #pragma unroll
  for (int nf = 0; nf < 4; ++nf) {
    const int col = n0 + wc*64 + nf*16 + fr;
    const float bv = bias[col];
    #pragma unroll
    for (int mf = 0; mf < 8; ++mf) {
      const int rowb = m0 + wr*128 + mf*16 + fq*4;
      #pragma unroll
      for (int r = 0; r < 4; ++r)
        C[(size_t)(rowb + r)*N + col] = acc[mf][nf][r] + bv;
    }
  }
}

extern "C" void kernel_launch(void* const* d_in, const int* in_sizes, int n_in,
                              void* d_out, int out_size, void* d_ws, size_t ws_size,
                              hipStream_t stream) {
  const float* x      = (const float*)d_in[0];   // (2,2048,4096)
  const float* W      = (const float*)d_in[1];   // (4096,4096)
  const float* bias   = (const float*)d_in[2];   // (4096)
  const float* boft_R = (const float*)d_in[3];   // (2,64,64,64)
  const float* boft_s = (const float*)d_in[4];   // (4096,1)
  float* out = (float*)d_out;

  char* ws = (char*)d_ws;
  float* Q    = (float*)ws;                        //  2 MB (128*64*64 f32)
  u16*   rotb = (u16*)  (ws + ((size_t)2  << 20)); //  1 MB (32*128*128 bf16)
  u16*   xb   = (u16*)  (ws + ((size_t)4  << 20)); // 32 MB
  u16*   swb  = (u16*)  (ws + ((size_t)36 << 20)); // 32 MB

  cayley_kernel  <<<128, 256, 0, stream>>>(boft_R, Q);
  rotbuild_kernel<<<dim3(32, 4), 256, 0, stream>>>(Q, rotb);
  prep_kernel    <<<3072, 256, 0, stream>>>(W, rotb, boft_s, swb, x, xb);
  gemm_kernel    <<<256, 512, 0, stream>>>(xb, swb, bias, out);
}